// Round 5
// baseline (313.682 us; speedup 1.0000x reference)
//
#include <hip/hip_runtime.h>

#define B_ 16
#define K_ 20
#define H_ 256
#define W_ 256
#define HW_ (H_*W_)
#define BK_ (B_*K_)
#define TH_ 18       // rows per strip (multiple of 9 -> static ring indices)
#define NSTRIP_ 15   // ceil(256/18); last strip masked

__device__ __forceinline__ float4 ld4(const float* p) { return *(const float4*)p; }
__device__ __forceinline__ float4 zero4() { return make_float4(0.f, 0.f, 0.f, 0.f); }

// exp(-(j-4)^2/50), j=0..8 (separable: exp(-(di^2+dj^2)/50) = g(di)*g(dj))
#define G0_ 0.72614903707f
#define G1_ 0.83527021141f
#define G2_ 0.92311634639f
#define G3_ 0.98019867331f
__device__ __constant__ const float Gc_[9] = {G0_, G1_, G2_, G3_, 1.0f, G3_, G2_, G1_, G0_};

// Read-optimal stats: block = (b, 4-row chunk). Inputs held in regs; labels
// streamed once per (k,row). Per-wave butterfly + atomics, k staggered per
// block to spread atomic addresses.
__global__ __launch_bounds__(256) void stats_k(const float* __restrict__ labels,
                                               const float* __restrict__ inputs,
                                               float* __restrict__ sums) {
    int idx = blockIdx.x;                 // 1024 blocks = 16 b * 64 chunks
    int b = idx >> 6, chunk = idx & 63;
    int tid = threadIdx.x, lane = tid & 63;
    int r = chunk * 4 + (tid >> 6);
    int off = r * W_ + lane * 4;

    const float* ip = inputs + (size_t)b * 3 * HW_;
    float4 a  = ld4(ip + off);
    float4 bb = ld4(ip + HW_ + off);
    float4 cc = ld4(ip + 2 * HW_ + off);
    const float* lp = labels + (size_t)b * K_ * HW_ + off;

    int kstart = idx % K_;                // stagger atomic targets
    for (int kk = 0; kk < K_; ++kk) {
        int k = kk + kstart; if (k >= K_) k -= K_;
        float4 l = ld4(lp + (size_t)k * HW_);
        float sl = (l.x + l.y) + (l.z + l.w);
        float s0 = l.x*a.x  + l.y*a.y  + l.z*a.z  + l.w*a.w;
        float s1 = l.x*bb.x + l.y*bb.y + l.z*bb.z + l.w*bb.w;
        float s2 = l.x*cc.x + l.y*cc.y + l.z*cc.z + l.w*cc.w;
#pragma unroll
        for (int o = 32; o > 0; o >>= 1) {
            sl += __shfl_xor(sl, o); s0 += __shfl_xor(s0, o);
            s1 += __shfl_xor(s1, o); s2 += __shfl_xor(s2, o);
        }
        if (lane == 0) {
            int bk = b * K_ + k;
            atomicAdd(&sums[bk], sl);
            atomicAdd(&sums[BK_ + bk], s0);
            atomicAdd(&sums[2*BK_ + bk], s1);
            atomicAdd(&sums[3*BK_ + bk], s2);
        }
    }
}

__device__ __forceinline__ float4 hblur9_f4(const float4& Lf, const float4& v, const float4& Rt) {
    const float G[9] = {G0_, G1_, G2_, G3_, 1.0f, G3_, G2_, G1_, G0_};
    float w[12] = {Lf.x, Lf.y, Lf.z, Lf.w, v.x, v.y, v.z, v.w, Rt.x, Rt.y, Rt.z, Rt.w};
    float4 o = zero4();
#pragma unroll
    for (int j = 0; j < 9; ++j) {
        o.x += G[j] * w[j];     o.y += G[j] * w[j + 1];
        o.z += G[j] * w[j + 2]; o.w += G[j] * w[j + 3];
    }
    return o;
}

// Adjoint: num = sum blur2d(l)*l*w, den = sum blur2d(l)*w.
// Wave-autonomous: one wave = (b,k,18-row strip); lane = 4 cols (float4);
// wave = full 256-col row. Raw-label ring[9] (float4, static indices via
// 9-unrolled inner loop); vblur in regs; hblur via 8 cross-lane shuffles.
// NO LDS, NO barriers in the main loop. Last block finalizes the loss.
__global__ __launch_bounds__(256) void fused_k(const float* __restrict__ labels,
                                               const float* __restrict__ inputs,
                                               const float* __restrict__ sums,
                                               float* __restrict__ numden,
                                               unsigned* __restrict__ counter,
                                               float* __restrict__ out) {
    const float G[9] = {G0_, G1_, G2_, G3_, 1.0f, G3_, G2_, G1_, G0_};
    int idx = blockIdx.x;                 // 1200 blocks
    int low = idx & 7; int t1 = idx >> 3; // XCD swizzle: same (b,strip) -> same XCD
    int kq = t1 % 5; int bsh = t1 / 5;
    int bs = bsh * 8 + low;               // 0..239 = b*15+strip
    int strip = bs % NSTRIP_, b = bs / NSTRIP_;
    int tid = threadIdx.x, lane = tid & 63, wv = tid >> 6;
    int k = kq * 4 + wv;                  // 4 waves share (b,strip) input rows
    int bk = b * K_ + k;

    float dn  = sums[bk] + 1e-5f * (float)HW_;
    float inv = 1.f / dn;
    float cm0 = sums[BK_ + bk] * inv;
    float cm1 = sums[2 * BK_ + bk] * inv;
    float cm2 = sums[3 * BK_ + bk] * inv;
    float m2  = cm0 * cm0 + cm1 * cm1 + cm2 * cm2;

    const float* lrow = labels + (size_t)bk * HW_;
    const float* i0p = inputs + (size_t)b * 3 * HW_;
    const float* i1p = i0p + HW_;
    const float* i2p = i0p + 2 * HW_;
    const int colo = lane * 4;
    const int r0 = strip * TH_;

    float4 ring[9];
#pragma unroll
    for (int i = 0; i < 8; ++i) {
        int t = r0 - 4 + i;
        ring[i] = ((unsigned)t < (unsigned)H_) ? ld4(lrow + t * W_ + colo) : zero4();
    }

    float4 nacc = zero4(), dacc = zero4();
    for (int rq = 0; rq < TH_ / 9; ++rq) {
#pragma unroll
        for (int u = 0; u < 9; ++u) {
            const int rr = rq * 9 + u;
            int t = r0 + rr + 4;
            ring[(u + 8) % 9] = (t < H_) ? ld4(lrow + t * W_ + colo) : zero4();
            int orow = r0 + rr;
            if (orow < H_) {              // wave-uniform; false only in last strip
                // vertical 9-tap on raw ring
                float4 vb = zero4();
#pragma unroll
                for (int j = 0; j < 9; ++j) {
                    const float4& rg = ring[(u + j) % 9];
                    vb.x += G[j]*rg.x; vb.y += G[j]*rg.y; vb.z += G[j]*rg.z; vb.w += G[j]*rg.w;
                }
                // horizontal 9-tap via neighbor-lane shuffles
                float4 Lf, Rt;
                Lf.x = __shfl_up(vb.x, 1); Lf.y = __shfl_up(vb.y, 1);
                Lf.z = __shfl_up(vb.z, 1); Lf.w = __shfl_up(vb.w, 1);
                Rt.x = __shfl_down(vb.x, 1); Rt.y = __shfl_down(vb.y, 1);
                Rt.z = __shfl_down(vb.z, 1); Rt.w = __shfl_down(vb.w, 1);
                if (lane == 0)  Lf = zero4();
                if (lane == 63) Rt = zero4();
                float4 bl = hblur9_f4(Lf, vb, Rt);
                const float4 lc = ring[(u + 4) % 9];   // raw label at output row
                int off = orow * W_ + colo;
                float4 a  = ld4(i0p + off);
                float4 bb = ld4(i1p + off);
                float4 cc = ld4(i2p + off);
                {
                    float df = (a.x*a.x + bb.x*bb.x + cc.x*cc.x)
                             - 2.f*(a.x*cm0 + bb.x*cm1 + cc.x*cm2) + m2;
                    float tt = bl.x * __expf(-(df*df));
                    dacc.x += tt; nacc.x += tt * lc.x;
                }
                {
                    float df = (a.y*a.y + bb.y*bb.y + cc.y*cc.y)
                             - 2.f*(a.y*cm0 + bb.y*cm1 + cc.y*cm2) + m2;
                    float tt = bl.y * __expf(-(df*df));
                    dacc.y += tt; nacc.y += tt * lc.y;
                }
                {
                    float df = (a.z*a.z + bb.z*bb.z + cc.z*cc.z)
                             - 2.f*(a.z*cm0 + bb.z*cm1 + cc.z*cm2) + m2;
                    float tt = bl.z * __expf(-(df*df));
                    dacc.z += tt; nacc.z += tt * lc.z;
                }
                {
                    float df = (a.w*a.w + bb.w*bb.w + cc.w*cc.w)
                             - 2.f*(a.w*cm0 + bb.w*cm1 + cc.w*cm2) + m2;
                    float tt = bl.w * __expf(-(df*df));
                    dacc.w += tt; nacc.w += tt * lc.w;
                }
            }
        }
    }

    float num = (nacc.x + nacc.y) + (nacc.z + nacc.w);
    float den = (dacc.x + dacc.y) + (dacc.z + dacc.w);
#pragma unroll
    for (int o = 32; o > 0; o >>= 1) { num += __shfl_xor(num, o); den += __shfl_xor(den, o); }
    if (lane == 0) {
        atomicAdd(&numden[k], num);
        atomicAdd(&numden[K_ + k], den);
    }
    __syncthreads();   // all 4 waves' atomics drained (vmcnt(0) before barrier)
    if (tid == 0) {
        __threadfence();
        unsigned done = atomicAdd(counter, 1u);
        if (done == gridDim.x - 1u) {     // last block: finalize
            __threadfence();
            float loss = 0.f;
            for (int kk = 0; kk < K_; ++kk) {
                float nu = atomicAdd(&numden[kk], 0.f);        // coherent read
                float de = atomicAdd(&numden[K_ + kk], 0.f);
                loss += fabsf(nu / (de + 1e-6f));
            }
            out[0] = (float)K_ - loss;
        }
    }
}

extern "C" void kernel_launch(void* const* d_in, const int* in_sizes, int n_in,
                              void* d_out, int out_size, void* d_ws, size_t ws_size,
                              hipStream_t stream) {
    const float* labels = (const float*)d_in[0];
    const float* inputs = (const float*)d_in[1];
    float* ws       = (float*)d_ws;
    float* sums     = ws;                        // 4*B*K floats
    float* numden   = ws + 4 * BK_;              // 2*K floats
    unsigned* counter = (unsigned*)(ws + 4 * BK_ + 2 * K_);

    hipMemsetAsync(ws, 0, (4 * BK_ + 2 * K_ + 1) * sizeof(float), stream);
    stats_k<<<1024, 256, 0, stream>>>(labels, inputs, sums);
    fused_k<<<NSTRIP_ * B_ * 5, 256, 0, stream>>>(labels, inputs, sums, numden,
                                                  counter, (float*)d_out);
}

// Round 6
// 219.445 us; speedup vs baseline: 1.4294x; 1.4294x over previous
//
#include <hip/hip_runtime.h>

#define B_ 16
#define K_ 20
#define H_ 256
#define W_ 256
#define HW_ (H_*W_)
#define BK_ (B_*K_)
#define TH_ 18       // rows per strip (9-unrolled inner loop -> static ring idx)
#define NSTRIP_ 15   // ceil(256/18); last strip partially masked

__device__ __forceinline__ float4 ld4(const float* p) { return *(const float4*)p; }
__device__ __forceinline__ float4 zero4() { return make_float4(0.f, 0.f, 0.f, 0.f); }

// exp(-(j-4)^2/50), j=0..8 (separable: exp(-(di^2+dj^2)/50) = g(di)*g(dj))
#define G0_ 0.72614903707f
#define G1_ 0.83527021141f
#define G2_ 0.92311634639f
#define G3_ 0.98019867331f

// Round-3-style stats: block = one (b,k,64-row chunk). Per-thread register
// accumulation (16 float4 iters), one butterfly, LDS combine, 4 atomics/block
// (-> ~8 serialized hits per address total). XCD swizzle keeps the 20 k-blocks
// that share (b,chunk) inputs on one XCD's L2.
__global__ __launch_bounds__(256) void stats_k(const float* __restrict__ labels,
                                               const float* __restrict__ inputs,
                                               float* __restrict__ sums) {
    int idx = blockIdx.x;                    // 1280 blocks
    int low = idx & 7; int t1 = idx >> 3;
    int k = t1 % K_; int bch = t1 / K_;      // bch in 0..7
    int bc = bch * 8 + low;                  // bc = chunk + 4*b, in 0..63
    int chunk = bc & 3, b = bc >> 2;

    int tid = threadIdx.x;
    int rowi = tid >> 6;                     // 4 rows in flight
    int colo = (tid & 63) * 4;

    const float* lrow = labels + ((size_t)(b * K_ + k)) * HW_;
    const float* ip   = inputs + (size_t)b * 3 * HW_;

    float sl = 0.f, s0 = 0.f, s1 = 0.f, s2 = 0.f;
    int r0 = chunk * 64 + rowi;
#pragma unroll 4
    for (int it = 0; it < 16; ++it) {
        int off = (r0 + it * 4) * W_ + colo;
        float4 l  = ld4(lrow + off);
        float4 a  = ld4(ip + off);
        float4 bb = ld4(ip + HW_ + off);
        float4 cc = ld4(ip + 2 * HW_ + off);
        sl += (l.x + l.y) + (l.z + l.w);
        s0 += l.x * a.x  + l.y * a.y  + l.z * a.z  + l.w * a.w;
        s1 += l.x * bb.x + l.y * bb.y + l.z * bb.z + l.w * bb.w;
        s2 += l.x * cc.x + l.y * cc.y + l.z * cc.z + l.w * cc.w;
    }
#pragma unroll
    for (int o = 32; o > 0; o >>= 1) {
        sl += __shfl_xor(sl, o); s0 += __shfl_xor(s0, o);
        s1 += __shfl_xor(s1, o); s2 += __shfl_xor(s2, o);
    }
    __shared__ float rb[4][4];
    int wv = tid >> 6, lane = tid & 63;
    if (lane == 0) { rb[0][wv] = sl; rb[1][wv] = s0; rb[2][wv] = s1; rb[3][wv] = s2; }
    __syncthreads();
    if (tid == 0) {
        int bk = b * K_ + k;
        atomicAdd(&sums[bk],          rb[0][0] + rb[0][1] + rb[0][2] + rb[0][3]);
        atomicAdd(&sums[BK_ + bk],    rb[1][0] + rb[1][1] + rb[1][2] + rb[1][3]);
        atomicAdd(&sums[2*BK_ + bk],  rb[2][0] + rb[2][1] + rb[2][2] + rb[2][3]);
        atomicAdd(&sums[3*BK_ + bk],  rb[3][0] + rb[3][1] + rb[3][2] + rb[3][3]);
    }
}

__device__ __forceinline__ float4 hblur9_f4(const float4& Lf, const float4& v, const float4& Rt) {
    const float G[9] = {G0_, G1_, G2_, G3_, 1.0f, G3_, G2_, G1_, G0_};
    float w[12] = {Lf.x, Lf.y, Lf.z, Lf.w, v.x, v.y, v.z, v.w, Rt.x, Rt.y, Rt.z, Rt.w};
    float4 o = zero4();
#pragma unroll
    for (int j = 0; j < 9; ++j) {
        o.x += G[j] * w[j];     o.y += G[j] * w[j + 1];
        o.z += G[j] * w[j + 2]; o.w += G[j] * w[j + 3];
    }
    return o;
}

// Adjoint: num = sum blur2d(l)*l*w, den = sum blur2d(l)*w.
// Wave-autonomous: one wave = (b,k,18-row strip); lane = 4 cols; wave = full row.
// Raw-label float4 ring[9], static indices; prefetch of row u+5 is committed
// to ring AFTER vblur so the global load has a full iteration of lead time.
// Epilogue: LDS-combine 4 waves -> ONE atomic pair per block.
__global__ __launch_bounds__(256) void fused_k(const float* __restrict__ labels,
                                               const float* __restrict__ inputs,
                                               const float* __restrict__ sums,
                                               float* __restrict__ numden) {
    const float G[9] = {G0_, G1_, G2_, G3_, 1.0f, G3_, G2_, G1_, G0_};
    int idx = blockIdx.x;                 // 1200 blocks
    int low = idx & 7; int t1 = idx >> 3; // XCD swizzle: same (b,strip) -> same XCD
    int kq = t1 % 5; int bsh = t1 / 5;
    int bs = bsh * 8 + low;               // 0..239 = b*15+strip
    int strip = bs % NSTRIP_, b = bs / NSTRIP_;
    int tid = threadIdx.x, lane = tid & 63, wv = tid >> 6;
    int k = kq * 4 + wv;                  // 4 waves share (b,strip) input rows
    int bk = b * K_ + k;

    float dn  = sums[bk] + 1e-5f * (float)HW_;
    float inv = 1.f / dn;
    float cm0 = sums[BK_ + bk] * inv;
    float cm1 = sums[2 * BK_ + bk] * inv;
    float cm2 = sums[3 * BK_ + bk] * inv;
    float m2  = cm0 * cm0 + cm1 * cm1 + cm2 * cm2;

    const float* lrow = labels + (size_t)bk * HW_;
    const float* i0p = inputs + (size_t)b * 3 * HW_;
    const float* i1p = i0p + HW_;
    const float* i2p = i0p + 2 * HW_;
    const int colo = lane * 4;
    const int r0 = strip * TH_;

    float4 ring[9];
#pragma unroll
    for (int i = 0; i < 9; ++i) {
        int t = r0 - 4 + i;
        ring[i] = ((unsigned)t < (unsigned)H_) ? ld4(lrow + t * W_ + colo) : zero4();
    }

    float4 nacc = zero4(), dacc = zero4();
    for (int rq = 0; rq < TH_ / 9; ++rq) {
#pragma unroll
        for (int u9 = 0; u9 < 9; ++u9) {
            const int rr = rq * 9 + u9;
            const int u = rr;             // ring phase (u9 == compile-time phase)
            // prefetch next ring row (for iteration u+1); commit after vblur
            int tnext = r0 + rr + 5;
            float4 nxt = (tnext < H_) ? ld4(lrow + tnext * W_ + colo) : zero4();
            int orow = r0 + rr;
            if (orow < H_) {              // wave-uniform; false only in last strip
                float4 vb = zero4();
#pragma unroll
                for (int j = 0; j < 9; ++j) {
                    const float4& rg = ring[(u9 + 1 + j) % 9];  // rows orow-4..orow+4
                    vb.x += G[j]*rg.x; vb.y += G[j]*rg.y; vb.z += G[j]*rg.z; vb.w += G[j]*rg.w;
                }
                float4 Lf, Rt;
                Lf.x = __shfl_up(vb.x, 1); Lf.y = __shfl_up(vb.y, 1);
                Lf.z = __shfl_up(vb.z, 1); Lf.w = __shfl_up(vb.w, 1);
                Rt.x = __shfl_down(vb.x, 1); Rt.y = __shfl_down(vb.y, 1);
                Rt.z = __shfl_down(vb.z, 1); Rt.w = __shfl_down(vb.w, 1);
                if (lane == 0)  Lf = zero4();
                if (lane == 63) Rt = zero4();
                float4 bl = hblur9_f4(Lf, vb, Rt);
                const float4 lc = ring[(u9 + 5) % 9];   // raw label at output row
                int off = orow * W_ + colo;
                float4 a  = ld4(i0p + off);
                float4 bb = ld4(i1p + off);
                float4 cc = ld4(i2p + off);
                {
                    float df = (a.x*a.x + bb.x*bb.x + cc.x*cc.x)
                             - 2.f*(a.x*cm0 + bb.x*cm1 + cc.x*cm2) + m2;
                    float tt = bl.x * __expf(-(df*df));
                    dacc.x += tt; nacc.x += tt * lc.x;
                }
                {
                    float df = (a.y*a.y + bb.y*bb.y + cc.y*cc.y)
                             - 2.f*(a.y*cm0 + bb.y*cm1 + cc.y*cm2) + m2;
                    float tt = bl.y * __expf(-(df*df));
                    dacc.y += tt; nacc.y += tt * lc.y;
                }
                {
                    float df = (a.z*a.z + bb.z*bb.z + cc.z*cc.z)
                             - 2.f*(a.z*cm0 + bb.z*cm1 + cc.z*cm2) + m2;
                    float tt = bl.z * __expf(-(df*df));
                    dacc.z += tt; nacc.z += tt * lc.z;
                }
                {
                    float df = (a.w*a.w + bb.w*bb.w + cc.w*cc.w)
                             - 2.f*(a.w*cm0 + bb.w*cm1 + cc.w*cm2) + m2;
                    float tt = bl.w * __expf(-(df*df));
                    dacc.w += tt; nacc.w += tt * lc.w;
                }
            }
            ring[(u9 + 1) % 9] = nxt;     // commit prefetch (slot of oldest row)
        }
    }

    float num = (nacc.x + nacc.y) + (nacc.z + nacc.w);
    float den = (dacc.x + dacc.y) + (dacc.z + dacc.w);
#pragma unroll
    for (int o = 32; o > 0; o >>= 1) { num += __shfl_xor(num, o); den += __shfl_xor(den, o); }
    // block-level combine: 4 waves -> one atomic pair (waves share k? NO: waves
    // have different k -> keep per-wave atomics but only 1 pair per wave, and
    // they target 4 different addresses; 4800 pairs /40 addr was the storm, so
    // combine the two values into wave-local single atomics only.
    if (lane == 0) {
        atomicAdd(&numden[k], num);
        atomicAdd(&numden[K_ + k], den);
    }
}

__global__ void finalize_k(const float* __restrict__ numden, float* __restrict__ out) {
    int x = threadIdx.x;          // 64 threads; lanes 0..19 each handle one k
    float v = 0.f;
    if (x < K_) v = fabsf(numden[x] / (numden[K_ + x] + 1e-6f));
#pragma unroll
    for (int o = 32; o > 0; o >>= 1) v += __shfl_xor(v, o);
    if (x == 0) out[0] = (float)K_ - v;
}

extern "C" void kernel_launch(void* const* d_in, const int* in_sizes, int n_in,
                              void* d_out, int out_size, void* d_ws, size_t ws_size,
                              hipStream_t stream) {
    const float* labels = (const float*)d_in[0];
    const float* inputs = (const float*)d_in[1];
    float* ws     = (float*)d_ws;
    float* sums   = ws;                        // 4*B*K floats
    float* numden = ws + 4 * BK_;              // 2*K floats

    hipMemsetAsync(ws, 0, (4 * BK_ + 2 * K_) * sizeof(float), stream);
    stats_k<<<1280, 256, 0, stream>>>(labels, inputs, sums);
    fused_k<<<NSTRIP_ * B_ * 5, 256, 0, stream>>>(labels, inputs, sums, numden);
    finalize_k<<<1, 64, 0, stream>>>(numden, (float*)d_out);
}